// Round 8
// baseline (174.306 us; speedup 1.0000x reference)
//
#include <hip/hip_runtime.h>
#include <hip/hip_bf16.h>

#define HID   64
#define BLOCK 256
#define NBLK  1024     // persistent-ish grid; 4096 wave-slots
#define TPW   16       // tokens per wave-tile (4 KB)

typedef short short8 __attribute__((ext_vector_type(8)));
typedef float floatx4 __attribute__((ext_vector_type(4)));

// two float4 -> bf16 short8 via packed RNE cvt
__device__ __forceinline__ short8 cvt8f(float4 f0, float4 f1) {
    union { __hip_bfloat162 h[4]; short8 s; } r;
    r.h[0] = __float22bfloat162_rn(make_float2(f0.x, f0.y));
    r.h[1] = __float22bfloat162_rn(make_float2(f0.z, f0.w));
    r.h[2] = __float22bfloat162_rn(make_float2(f1.x, f1.y));
    r.h[3] = __float22bfloat162_rn(make_float2(f1.z, f1.w));
    return r.s;
}

#define SB __builtin_amdgcn_sched_barrier(0)

// LINE-DENSE global read of one 4 KB wave-tile: lane -> base + lane*16B,
// 4 instrs x 1 KB, every 64B line fully covered by 4 consecutive lanes.
#define GLOAD(dst, wt) do {                                                       \
    const float* gp_ = x + (long)(wt) * (TPW * HID);                              \
    _Pragma("unroll")                                                             \
    for (int j = 0; j < 4; ++j)                                                   \
        dst[j] = *(const float4*)(gp_ + j * 256 + lane * 4);                      \
    } while (0)

#define MODLD(dst, wt) (dst) = mod[(long)(wt) * TPW + r15]

// ds_write (XOR slot swizzle) -> ds_read fragments -> cvt -> 24 MFMA -> select
// -> line-complete stores. Swizzle: 16B slot s within a 256B row stored at
// s ^ (row & 15); write and read both apply it (rule 21), <=2-way banks.
#define SHUFCOMP(g, mv, wt, ph) do {                                              \
    float* sb_ = &sbuf[wave][ph][0];                                              \
    _Pragma("unroll")                                                             \
    for (int j = 0; j < 4; ++j) {                                                 \
        const int row_ = j * 4 + kg;          /* linear offset>>8 */              \
        const int sl_  = (lane & 15) ^ row_;  /* linear slot ^ row */             \
        *(float4*)&sb_[row_ * 64 + sl_ * 4] = g[j];                               \
    }                                                                             \
    const int rb_ = r15 * 64;                                                     \
    const float4 q00 = *(const float4*)&sb_[rb_ + (((kg * 2 + 0) ^ r15)) * 4];    \
    const float4 q01 = *(const float4*)&sb_[rb_ + (((kg * 2 + 1) ^ r15)) * 4];    \
    const float4 q10 = *(const float4*)&sb_[rb_ + (((kg * 2 + 8) ^ r15)) * 4];    \
    const float4 q11 = *(const float4*)&sb_[rb_ + (((kg * 2 + 9) ^ r15)) * 4];    \
    const short8 xb0 = cvt8f(q00, q01);                                           \
    const short8 xb1 = cvt8f(q10, q11);                                           \
    const int m_ = (mv);                                                          \
    float* ob_ = out + ((long)(wt) * TPW + r15) * HID + kg * 4;                   \
    _Pragma("unroll")                                                             \
    for (int nt = 0; nt < 4; ++nt) {                                              \
        floatx4 a0 = {0.f,0.f,0.f,0.f}, a1 = {0.f,0.f,0.f,0.f},                   \
                a2 = {0.f,0.f,0.f,0.f};                                           \
        a0 = __builtin_amdgcn_mfma_f32_16x16x32_bf16(wa[0][nt][0], xb0, a0,0,0,0);\
        a0 = __builtin_amdgcn_mfma_f32_16x16x32_bf16(wa[0][nt][1], xb1, a0,0,0,0);\
        a1 = __builtin_amdgcn_mfma_f32_16x16x32_bf16(wa[1][nt][0], xb0, a1,0,0,0);\
        a1 = __builtin_amdgcn_mfma_f32_16x16x32_bf16(wa[1][nt][1], xb1, a1,0,0,0);\
        a2 = __builtin_amdgcn_mfma_f32_16x16x32_bf16(wa[2][nt][0], xb0, a2,0,0,0);\
        a2 = __builtin_amdgcn_mfma_f32_16x16x32_bf16(wa[2][nt][1], xb1, a2,0,0,0);\
        const floatx4 v_ = (m_ == 0) ? a0 : ((m_ == 1) ? a1 : a2);                \
        *(floatx4*)(ob_ + nt * 16) = v_;                                          \
    } } while (0)

__global__ __launch_bounds__(BLOCK) void moe_dense(
    const float* __restrict__ x,
    const float* __restrict__ W,
    const int* __restrict__ mod,
    float* __restrict__ out)
{
    __shared__ float sbuf[4][2][1024];   // [wave][phase][4 KB] = 32 KB

    const int tid  = threadIdx.x;
    const int wave = tid >> 6;
    const int lane = tid & 63;
    const int r15  = lane & 15;          // token within tile / MFMA col
    const int kg   = lane >> 4;          // k-group 0..3

    // ---- W fragments: once per persistent block (amortized over 256 tiles) ----
    short8 wa[3][4][2];
#pragma unroll
    for (int mm = 0; mm < 3; ++mm)
#pragma unroll
        for (int nt = 0; nt < 4; ++nt) {
            const float* wp = W + mm * 4096 + (nt * 16 + r15) * HID + kg * 8;
            wa[mm][nt][0] = cvt8f(*(const float4*)wp,        *(const float4*)(wp + 4));
            wa[mm][nt][1] = cvt8f(*(const float4*)(wp + 32), *(const float4*)(wp + 36));
        }

    const int  n_wt   = (1 << 20) / TPW;         // 65536 wave-tiles
    const long stride = (long)NBLK * 4;          // 4096 wave-slots
    const long wt0    = (long)blockIdx.x * 4 + wave;
    const int  witer  = n_wt / (int)stride;      // 16 (even)

    float4 gA[4], gB[4];
    int    mA, mB;

    GLOAD(gA, wt0); MODLD(mA, wt0); SB;

#pragma unroll 1
    for (int it = 0; it < witer; it += 2) {
        const long wtA = wt0 + (long)it * stride;
        const long wtB = wtA + stride;

        GLOAD(gB, wtB); MODLD(mB, wtB); SB;      // prefetch B while computing A
        SHUFCOMP(gA, mA, wtA, 0); SB;

        if (it + 2 < witer) {                    // prefetch next A while computing B
            const long wtN = wt0 + (long)(it + 2) * stride;
            GLOAD(gA, wtN); MODLD(mA, wtN);
        }
        SB;
        SHUFCOMP(gB, mB, wtB, 1); SB;
    }
}

extern "C" void kernel_launch(void* const* d_in, const int* in_sizes, int n_in,
                              void* d_out, int out_size, void* d_ws, size_t ws_size,
                              hipStream_t stream) {
    const float* x   = (const float*)d_in[0];
    const float* W   = (const float*)d_in[1];
    const int*   mod = (const int*)d_in[2];
    float*       out = (float*)d_out;

    moe_dense<<<NBLK, BLOCK, 0, stream>>>(x, W, mod, out);
}

// Round 9
// 118.741 us; speedup vs baseline: 1.4679x; 1.4679x over previous
//
#include <hip/hip_runtime.h>
#include <hip/hip_bf16.h>

#define HID   64
#define BLOCK 256
#define GPB   8      // 64-token tiles per block -> 2048 blocks
#define NBUF  3      // triple buffer: prefetch distance 2

typedef short short8 __attribute__((ext_vector_type(8)));
typedef float floatx4 __attribute__((ext_vector_type(4)));

__device__ __forceinline__ short8 cvt8f(float4 f0, float4 f1) {
    union { __hip_bfloat162 h[4]; short8 s; } r;
    r.h[0] = __float22bfloat162_rn(make_float2(f0.x, f0.y));
    r.h[1] = __float22bfloat162_rn(make_float2(f0.z, f0.w));
    r.h[2] = __float22bfloat162_rn(make_float2(f1.x, f1.y));
    r.h[3] = __float22bfloat162_rn(make_float2(f1.z, f1.w));
    return r.s;
}

__device__ __forceinline__ void gload_lds16(const float* g, float* l) {
    __builtin_amdgcn_global_load_lds(
        (const __attribute__((address_space(1))) void*)g,
        (__attribute__((address_space(3))) void*)l, 16, 0, 0);
}

#define SB __builtin_amdgcn_sched_barrier(0)
#define BUF(g) ((g) % NBUF)

// Block-cooperative stage of tile g (64 tokens, 16 KB): wave w loads chunks
// w*4..w*4+3. Consumption-order layout (rule 21: pre-swizzled global src,
// linear LDS dest): chunk c = mt*4 + kc*2 + hf holds, at lane slot,
// x[orig + mt*16 + r15][kg*8 + kc*32 + hf*4 .. +4)
#define STAGE(g) do {                                                             \
    const long orig_ = blk0 + (g) * 64;                                           \
    _Pragma("unroll")                                                             \
    for (int i = 0; i < 4; ++i) {                                                 \
        const int kc_ = i >> 1, hf_ = i & 1;                                      \
        const float* src_ = x + (orig_ + wave * 16 + r15) * HID                   \
                              + kg * 8 + kc_ * 32 + hf_ * 4;                      \
        gload_lds16(src_, &sbuf[BUF(g)][(wave * 4 + i) * 256]);                   \
    } } while (0)

// mod loads for tile g (4 per lane), 2 iterations ahead of use; unpinned —
// they ride the vmcnt queue at fixed positions.
#define MODL(g) do {                                                              \
    const long orig_ = blk0 + (g) * 64;                                           \
    _Pragma("unroll")                                                             \
    for (int mt = 0; mt < 4; ++mt)                                                \
        mv[g][mt] = mod[orig_ + mt * 16 + r15];                                   \
    } while (0)

// Compute tile g: this wave's 16 output cols x 64 tokens; 3 modalities, select.
#define COMPUTE(g) do {                                                           \
    const long orig_ = blk0 + (g) * 64;                                           \
    _Pragma("unroll")                                                             \
    for (int mt = 0; mt < 4; ++mt) {                                              \
        const float4 q0 = *(const float4*)&sbuf[BUF(g)][(mt*4+0)*256 + lane*4];   \
        const float4 q1 = *(const float4*)&sbuf[BUF(g)][(mt*4+1)*256 + lane*4];   \
        const float4 q2 = *(const float4*)&sbuf[BUF(g)][(mt*4+2)*256 + lane*4];   \
        const float4 q3 = *(const float4*)&sbuf[BUF(g)][(mt*4+3)*256 + lane*4];   \
        const short8 xb0 = cvt8f(q0, q1);                                         \
        const short8 xb1 = cvt8f(q2, q3);                                         \
        floatx4 a0 = {0.f,0.f,0.f,0.f}, a1 = {0.f,0.f,0.f,0.f},                   \
                a2 = {0.f,0.f,0.f,0.f};                                           \
        a0 = __builtin_amdgcn_mfma_f32_16x16x32_bf16(wa[0][0], xb0, a0,0,0,0);    \
        a0 = __builtin_amdgcn_mfma_f32_16x16x32_bf16(wa[0][1], xb1, a0,0,0,0);    \
        a1 = __builtin_amdgcn_mfma_f32_16x16x32_bf16(wa[1][0], xb0, a1,0,0,0);    \
        a1 = __builtin_amdgcn_mfma_f32_16x16x32_bf16(wa[1][1], xb1, a1,0,0,0);    \
        a2 = __builtin_amdgcn_mfma_f32_16x16x32_bf16(wa[2][0], xb0, a2,0,0,0);    \
        a2 = __builtin_amdgcn_mfma_f32_16x16x32_bf16(wa[2][1], xb1, a2,0,0,0);    \
        const int m_ = mv[g][mt];                                                 \
        const floatx4 v_ = (m_ == 0) ? a0 : ((m_ == 1) ? a1 : a2);                \
        *(floatx4*)(out + (orig_ + mt * 16 + r15) * HID + wave * 16 + kg * 4)     \
            = v_;                                                                 \
    } } while (0)

#define WAITV(N) asm volatile("s_waitcnt vmcnt(" #N ")" ::: "memory")

// Steady-state iteration. Exact counts: at WAIT, ops younger than tile g's
// stage+mod = stores(g-2) 4 + stage/mod(g+1) 8 + stores(g-1) 4 + stage/mod(g+2)
// 8 = 24 (less at the pipeline edges). Stores are never waited on.
#define ITER(g, K)                                                                \
    STAGE((g) + 2); SB; MODL((g) + 2); SB;                                        \
    WAITV(K); __builtin_amdgcn_s_barrier(); SB;                                   \
    COMPUTE(g); SB;                                                               \
    __builtin_amdgcn_s_barrier(); SB;      /* buf[(g)%3] free for stage(g+3) */

#define ITER_TAIL(g, K)                                                           \
    WAITV(K); __builtin_amdgcn_s_barrier(); SB;                                   \
    COMPUTE(g); SB;                                                               \
    __builtin_amdgcn_s_barrier(); SB;

__global__ __launch_bounds__(BLOCK) void moe_deep(
    const float* __restrict__ x,
    const float* __restrict__ W,
    const int* __restrict__ mod,
    float* __restrict__ out)
{
    __shared__ float sbuf[NBUF][16 * 256];   // 3 x 16 KB = 48 KB

    const int tid  = threadIdx.x;
    const int wave = tid >> 6;
    const int lane = tid & 63;
    const int r15  = lane & 15;              // token within 16-group / MFMA col
    const int kg   = lane >> 4;              // k-group 0..3

    const long blk0 = (long)blockIdx.x * (64 * GPB);

    int mv[GPB][4];                          // all indices compile-time (full unroll)

    // ---- prologue: W first (its drain happens before any stage is queued) ----
    short8 wa[3][2];
#pragma unroll
    for (int mm = 0; mm < 3; ++mm) {
        const float* wp = W + mm * 4096 + (wave * 16 + r15) * HID + kg * 8;
        wa[mm][0] = cvt8f(*(const float4*)wp,        *(const float4*)(wp + 4));
        wa[mm][1] = cvt8f(*(const float4*)(wp + 32), *(const float4*)(wp + 36));
    }
    SB;

    // stage tiles 0,1 + their mods: queue = [s0(4) m0(4) s1(4) m1(4)]
    STAGE(0); SB; MODL(0); SB;
    STAGE(1); SB; MODL(1); SB;

    ITER(0, 16)   // +s2,m2 (8): younger-than-{s0,m0} = 16
    ITER(1, 20)   // stores0(4) + s3,m3(8) + s2,m2(8) = 20
    ITER(2, 24) ITER(3, 24) ITER(4, 24) ITER(5, 24)
    ITER_TAIL(6, 16)  // stores4(4) + s7,m7(8) + stores5(4) = 16
    WAITV(8); __builtin_amdgcn_s_barrier(); SB;   // stores5(4)+stores6(4) = 8
    COMPUTE(7);
}

extern "C" void kernel_launch(void* const* d_in, const int* in_sizes, int n_in,
                              void* d_out, int out_size, void* d_ws, size_t ws_size,
                              hipStream_t stream) {
    const float* x   = (const float*)d_in[0];
    const float* W   = (const float*)d_in[1];
    const int*   mod = (const int*)d_in[2];
    float*       out = (float*)d_out;

    const int n      = in_sizes[0] / HID;     // tokens (1<<20)
    const int blocks = n / (64 * GPB);        // 2048

    moe_deep<<<blocks, BLOCK, 0, stream>>>(x, W, mod, out);
}